// Round 15
// baseline (380.196 us; speedup 1.0000x reference)
//
#include <hip/hip_runtime.h>
#include <math.h>

#define BB 32
#define TT 128
#define HH 256
#define MM 1000

typedef __attribute__((ext_vector_type(8))) short short8;
typedef __attribute__((ext_vector_type(4))) float floatx4;

__device__ inline void fma4(float4& a, const float4 b, float s) {
    a.x += b.x * s; a.y += b.y * s; a.z += b.z * s; a.w += b.w * s;
}

__device__ inline unsigned short f2bf(float f) {
    union { float f; unsigned int u; } c; c.f = f;
    unsigned int u = c.u;
    return (unsigned short)((u + 0x7FFFu + ((u >> 16) & 1u)) >> 16);
}

__device__ inline float bf2f(unsigned short h) {
    union { unsigned int u; float f; } c; c.u = ((unsigned int)h) << 16; return c.f;
}

// ---------------- ws layout (floats) ----------------
// e_cum 0 (4096) | baseq 36864 (16384) | basep 53248 (8192)
// h 61440 (1048576)
// pw_h/pw_l @1110016/1372160 | A2T (ushort) @float 1634304 ([(b*4+q)][n=512][t=128])
// wc8 5828608 | P2o 6084608 | bvec 6088704 | ml_i 6089216
// PWpart 6090752 (2097152) | w_bf (ushort) @float 8187904 ([(b*4+q)][1024][128])
// x_hi @16576512 (524288) | x_lo @17100800 (524288)
// high-water: 17,625,088 floats = 70.5 MB
// R15 = R14 resubmission (R14 failed on infra, audit clean — same precedent as R6->R7).

// ===== kF1: k_h+xcvt [0,256) | k_pw_part [256,768) | k_prep [768,800)
__global__ __launch_bounds__(256) void kF1(
    const float* __restrict__ x, const float* __restrict__ pw_h_,
    const float* __restrict__ pb_h, float* __restrict__ h,
    const float* __restrict__ p1w, const float* __restrict__ po,
    float* __restrict__ PWpart,
    unsigned short* __restrict__ xh, unsigned short* __restrict__ xl,
    const float* __restrict__ dur, float* __restrict__ e_cum,
    int* __restrict__ ml_i, float* __restrict__ ml_out,
    unsigned short* __restrict__ w_bf) {
    __shared__ __align__(16) float S1[4096];   // 16 KB union
    int gb = blockIdx.x;
    int tid = threadIdx.x;

    if (gb < 256) {
        // ---- k_h: h = x @ proj_w + proj_b ; also emit x_hi/x_lo for this tile ----
        float (*xs)[HH] = (float(*)[HH])S1;
        int b = gb >> 3, tt = gb & 7;
        int t0 = tt * 16;
        for (int e = tid; e < 16 * HH; e += 256) {
            int r = e >> 8, i = e & 255;
            xs[r][i] = x[(b * TT + t0 + r) * HH + i];
        }
        __syncthreads();
        // xcvt: each thread converts 16 consecutive elements of one row
        {
            int r = tid >> 4, i0 = (tid & 15) * 16;
            union { unsigned short us[16]; uint4 v[2]; } He, Lo;
            #pragma unroll
            for (int k = 0; k < 16; ++k) {
                float xv = xs[r][i0 + k];
                unsigned short hv = f2bf(xv);
                He.us[k] = hv;
                Lo.us[k] = f2bf(xv - bf2f(hv));
            }
            size_t off = ((size_t)(b * TT + t0 + r)) * 256 + i0;
            *(uint4*)(xh + off) = He.v[0];
            *(uint4*)(xh + off + 8) = He.v[1];
            *(uint4*)(xl + off) = Lo.v[0];
            *(uint4*)(xl + off + 8) = Lo.v[1];
        }
        int jg = tid & 63, rg = tid >> 6;
        int j4 = jg * 4;
        float4 bias = *(const float4*)(pb_h + j4);
        float4 acc[4];
        #pragma unroll
        for (int ri = 0; ri < 4; ++ri) acc[ri] = bias;
        #pragma unroll 4
        for (int i = 0; i < HH; ++i) {
            float4 wv = *(const float4*)(pw_h_ + i * HH + j4);
            #pragma unroll
            for (int ri = 0; ri < 4; ++ri) fma4(acc[ri], wv, xs[rg * 4 + ri][i]);
        }
        #pragma unroll
        for (int ri = 0; ri < 4; ++ri)
            *(float4*)(h + (b * TT + t0 + rg * 4 + ri) * HH + j4) = acc[ri];
    } else if (gb < 768) {
        // ---- k_pw_part ----
        float (*S)[64] = (float(*)[64])S1;
        int blk = gb - 256;
        int ks = blk & 3, colT = (blk >> 2) & 7, ht = blk >> 5;
        int q = colT >> 1, j0 = (colT & 1) * 256;
        int h0 = ht * 16, k0 = ks * 64;
        for (int e = tid; e < 1024; e += 256) {
            int r = e >> 6, c = e & 63;
            S[r][c] = p1w[(q * 256 + h0 + r) * 256 + k0 + c];
        }
        __syncthreads();
        int jg = tid & 63, rg = tid >> 6;
        int jcol = j0 + jg * 4;
        float4 acc[4];
        #pragma unroll
        for (int r = 0; r < 4; ++r) acc[r] = make_float4(0, 0, 0, 0);
        float4 nb = *(const float4*)(po + (size_t)k0 * 512 + jcol);
        for (int c = 0; c < 64; ++c) {
            float4 cur = nb;
            if (c < 63) nb = *(const float4*)(po + (size_t)(k0 + c + 1) * 512 + jcol);
            #pragma unroll
            for (int r = 0; r < 4; ++r) fma4(acc[r], cur, S[rg * 4 + r][c]);
        }
        #pragma unroll
        for (int r = 0; r < 4; ++r) {
            int hh = h0 + rg * 4 + r;
            *(float4*)(PWpart + (size_t)ks * 524288 + hh * 2048 + q * 512 + jcol) = acc[r];
        }
    } else {
        // ---- k_prep ----
        int b = gb - 768;
        if (tid < 64) {
            #pragma unroll
            for (int q = 0; q < 4; ++q) {
                uint4* dst = (uint4*)(w_bf + (((size_t)(b * 4 + q)) * 1024 + 1000) * 128);
                for (int e = tid; e < 384; e += 64) dst[e] = make_uint4(0, 0, 0, 0);
            }
            if (tid == 0) {
                float run = 0.f;
                const float* d = dur + b * TT;
                float* e = e_cum + b * TT;
                for (int t = 0; t < TT; ++t) { run += d[t]; e[t] = run; }
                int ml = (int)rintf(run);
                if (ml > MM) ml = MM;
                if (ml < 0) ml = 0;
                ml_i[b] = ml;
                ml_out[b] = (float)ml;
            }
        }
    }
}

// ===== kF2: k_conv+k_bases fused [0,256) | k_pwt [256,384) | k_small [384] =====
__global__ __launch_bounds__(256) void kF2(
    const float* __restrict__ h, const float* __restrict__ cw,
    const int* __restrict__ xlen,
    const float* __restrict__ PWpart,
    unsigned short* __restrict__ pwh, unsigned short* __restrict__ pwl,
    const float* __restrict__ p2w, const float* __restrict__ po,
    const float* __restrict__ p1b, const float* __restrict__ p2b,
    const float* __restrict__ pob,
    float* __restrict__ P2o, float* __restrict__ bvec,
    const float* __restrict__ cb, const float* __restrict__ cg,
    const float* __restrict__ cbeta,
    const float* __restrict__ qw1, const float* __restrict__ qb1,
    const float* __restrict__ pw1, const float* __restrict__ pb1,
    const float* __restrict__ e_cum, const float* __restrict__ dur,
    float* __restrict__ baseq, float* __restrict__ basep) {
    __shared__ __align__(16) float S2[10906];   // 43.6 KB union
    int gb = blockIdx.x;
    int tid = threadIdx.x;

    if (gb < 256) {
        // ---- conv + bases ----
        float (*hs)[257] = (float(*)[257])S2;            // 18*257 = 4626
        float (*cws)[769] = (float(*)[769])(S2 + 4626);  // 8*769  = 6152
        float (*hc)[8] = (float(*)[8])(S2 + 10778);      // 16*8   = 128
        int b = gb >> 3, tt = gb & 7;
        int t0 = tt * 16;
        int L = xlen[b];
        for (int e = tid; e < 18 * 256; e += 256) {
            int r = e >> 8, i = e & 255;
            int t = t0 - 1 + r;
            float v = 0.f;
            if (t >= 0 && t < TT && t < L) v = h[((size_t)b * TT + t) * HH + i];
            hs[r][i] = v;
        }
        for (int e = tid; e < 6144; e += 256) {
            int o = e / 768, rem = e - o * 768;
            cws[o][rem] = cw[e];
        }
        __syncthreads();
        if (tid < 128) {
            int o = tid >> 4, tl = tid & 15;
            float acc = 0.f;
            #pragma unroll
            for (int k = 0; k < 3; ++k) {
                const float* wr = &cws[o][k];
                const float* hr = hs[tl + k];
                #pragma unroll 8
                for (int i = 0; i < 256; ++i) acc += hr[i] * wr[i * 3];
            }
            hc[tl][o] = acc;
        }
        __syncthreads();
        if (tid < 16) {
            int t = t0 + tid;
            float v[8];
            float mu = 0.f;
            #pragma unroll
            for (int o = 0; o < 8; ++o) { v[o] = hc[tid][o] + cb[o]; mu += v[o]; }
            mu *= 0.125f;
            float var = 0.f;
            #pragma unroll
            for (int o = 0; o < 8; ++o) { float d = v[o] - mu; var += d * d; }
            var *= 0.125f;
            float rs = 1.0f / sqrtf(var + 1e-5f);
            float valid = (t < L) ? 1.f : 0.f;
            #pragma unroll
            for (int o = 0; o < 8; ++o) {
                float a = (v[o] - mu) * rs * cg[o] + cbeta[o];
                v[o] = a / (1.f + expf(-a)) * valid;
            }
            float e = e_cum[b * TT + t];
            float s_ = e - dur[b * TT + t];
            #pragma unroll
            for (int j = 0; j < 4; ++j) {
                float acc = qb1[j];
                #pragma unroll
                for (int o = 0; o < 8; ++o) acc += v[o] * qw1[o * 4 + j];
                acc += e * qw1[9 * 4 + j] - s_ * qw1[8 * 4 + j];
                baseq[(b * TT + t) * 4 + j] = acc;
            }
            #pragma unroll
            for (int j = 0; j < 2; ++j) {
                float acc = pb1[j];
                #pragma unroll
                for (int o = 0; o < 8; ++o) acc += v[o] * pw1[o * 2 + j];
                acc += e * pw1[9 * 2 + j] - s_ * pw1[8 * 2 + j];
                basep[(b * TT + t) * 2 + j] = acc;
            }
        }
    } else if (gb < 384) {
        // ---- k_pwt ----
        float (*S)[65] = (float(*)[65])S2;   // 64*65 = 4160
        int blk = gb - 256;
        int nt = blk & 31, ct = blk >> 5;
        int c0 = ct * 64, n0 = nt * 64;
        for (int e = tid; e < 4096; e += 256) {
            int cc = e >> 6, nn = e & 63;
            size_t off = (size_t)(c0 + cc) * 2048 + n0 + nn;
            float v = PWpart[off] + PWpart[524288 + off]
                    + PWpart[2 * 524288 + off] + PWpart[3 * 524288 + off];
            S[cc][nn] = v;
        }
        __syncthreads();
        for (int e = tid; e < 4096; e += 256) {
            int nn = e >> 6, cc = e & 63;
            float v = S[cc][nn];
            unsigned short hv = f2bf(v);
            size_t d = (size_t)(n0 + nn) * 256 + c0 + cc;
            pwh[d] = hv;
            pwl[d] = f2bf(v - bf2f(hv));
        }
    } else {
        // ---- k_small, 256-thread variant ----
        for (int j = tid; j < 512; j += 256) {
            float acc[9];
            #pragma unroll
            for (int r = 0; r < 9; ++r) acc[r] = 0.f;
            for (int c = 0; c < HH; ++c) {
                float pv = po[c * 512 + j];
                #pragma unroll
                for (int r = 0; r < 8; ++r) acc[r] += p2w[r * HH + c] * pv;
                acc[8] += (p1b[c] + p2b[c]) * pv;
            }
            #pragma unroll
            for (int r = 0; r < 8; ++r) P2o[r * 512 + j] = acc[r];
            bvec[j] = acc[8] + pob[j];
        }
    }
}

// XOR-swizzled ushort index into a [128 rows][32 k] LDS tile (16B chunk granularity).
__device__ inline int swzk(int row, int chunk) {
    return row * 32 + ((chunk ^ ((row >> 1) & 3)) << 3);
}

// ===== kF3: k_A2m [0,512) | k_wsoft [512,8512) =====  (R11/R13-proven form)
__global__ __launch_bounds__(256) void kF3(
    const unsigned short* __restrict__ xh, const unsigned short* __restrict__ xl,
    const unsigned short* __restrict__ pwh, const unsigned short* __restrict__ pwl,
    unsigned short* __restrict__ A2T,
    const float* __restrict__ baseq, const float* __restrict__ basep,
    const float* __restrict__ qw1, const float* __restrict__ qg,
    const float* __restrict__ qbeta, const float* __restrict__ qw2,
    const float* __restrict__ qb2,
    const float* __restrict__ pw1, const float* __restrict__ pg,
    const float* __restrict__ pbeta, const float* __restrict__ pw2,
    const float* __restrict__ pb2,
    const int* __restrict__ xlen, const int* __restrict__ ml_i,
    float* __restrict__ w_out, float* __restrict__ mm_out,
    float* __restrict__ wc8, unsigned short* __restrict__ w_bf) {
    __shared__ __align__(16) unsigned short SM[16384];   // 32 KB (A2m branch only)
    int gblk = blockIdx.x;
    int tid = threadIdx.x;

    if (gblk >= 512) {
        // ---- wsoft branch (barrier-free, R9-proven body) ----
        int blk = gblk - 512;            // b*250 + mg
        int b = blk / 250;
        int mg = blk - b * 250;
        int wv = tid >> 6, lane = tid & 63;
        int m = mg * 4 + wv;
        int ml = ml_i[b];
        int t1 = lane, t2 = lane + 64;
        bool pad = (m >= ml);
        size_t mmbase = ((size_t)b * MM + m) * TT;
        mm_out[mmbase + t1] = pad ? 1.f : 0.f;
        mm_out[mmbase + t2] = pad ? 1.f : 0.f;
        if (pad) {
            #pragma unroll
            for (int q = 0; q < 4; ++q) {
                size_t wb = ((size_t)(b * 4 + q) * MM + m) * TT;
                w_out[wb + t1] = 0.f;
                w_out[wb + t2] = 0.f;
                unsigned short* wbq = w_bf + (((size_t)(b * 4 + q)) * 1024 + m) * 128;
                wbq[t1] = 0; wbq[t2] = 0;
            }
            if (lane == 0) {
                #pragma unroll
                for (int r = 0; r < 8; ++r) wc8[((size_t)b * MM + m) * 8 + r] = 0.f;
            }
            return;
        }
        int L = xlen[b];
        float mp1 = (float)(m + 1);
        float dq[4];
        #pragma unroll
        for (int j = 0; j < 4; ++j) dq[j] = mp1 * (qw1[8 * 4 + j] - qw1[9 * 4 + j]);

        float sc1[4], sc2[4];
        float c1v[2], c2v[2];
        #pragma unroll
        for (int half = 0; half < 2; ++half) {
            int t = half ? t2 : t1;
            float* sc = half ? sc2 : sc1;
            float* cv = half ? c2v : c1v;
            if (t < L) {
                float4 bq = *(const float4*)(baseq + ((size_t)b * TT + t) * 4);
                float z[4] = {bq.x + dq[0], bq.y + dq[1], bq.z + dq[2], bq.w + dq[3]};
                float mu = 0.25f * (z[0] + z[1] + z[2] + z[3]);
                float var = 0.f;
                #pragma unroll
                for (int j = 0; j < 4; ++j) { float d = z[j] - mu; var += d * d; }
                var *= 0.25f;
                float rs = 1.f / sqrtf(var + 1e-5f);
                float a[4];
                #pragma unroll
                for (int j = 0; j < 4; ++j) {
                    float av = (z[j] - mu) * rs * qg[j] + qbeta[j];
                    a[j] = av / (1.f + expf(-av));
                }
                #pragma unroll
                for (int q = 0; q < 4; ++q) {
                    float s = qb2[q];
                    #pragma unroll
                    for (int j = 0; j < 4; ++j) s += a[j] * qw2[j * 4 + q];
                    sc[q] = s;
                }
                float z0 = basep[((size_t)b * TT + t) * 2 + 0] + mp1 * (pw1[16] - pw1[18]);
                float z1 = basep[((size_t)b * TT + t) * 2 + 1] + mp1 * (pw1[17] - pw1[19]);
                float pmu = 0.5f * (z0 + z1);
                float d0 = z0 - pmu, d1 = z1 - pmu;
                float pvar = 0.5f * (d0 * d0 + d1 * d1);
                float prs = 1.f / sqrtf(pvar + 1e-5f);
                float a0 = d0 * prs * pg[0] + pbeta[0];
                float a1 = d1 * prs * pg[1] + pbeta[1];
                a0 = a0 / (1.f + expf(-a0));
                a1 = a1 / (1.f + expf(-a1));
                cv[0] = pb2[0] + a0 * pw2[0] + a1 * pw2[2];
                cv[1] = pb2[1] + a0 * pw2[1] + a1 * pw2[3];
            } else {
                sc[0] = sc[1] = sc[2] = sc[3] = -__builtin_inff();
                cv[0] = cv[1] = 0.f;
            }
        }
        float w1[4], w2[4];
        #pragma unroll
        for (int q = 0; q < 4; ++q) {
            float mx = fmaxf(sc1[q], sc2[q]);
            #pragma unroll
            for (int off = 32; off > 0; off >>= 1) mx = fmaxf(mx, __shfl_xor(mx, off, 64));
            float e1 = expf(sc1[q] - mx);
            float e2 = expf(sc2[q] - mx);
            float s = e1 + e2;
            #pragma unroll
            for (int off = 32; off > 0; off >>= 1) s += __shfl_xor(s, off, 64);
            w1[q] = e1 / s;
            w2[q] = e2 / s;
            size_t wb = ((size_t)(b * 4 + q) * MM + m) * TT;
            w_out[wb + t1] = w1[q];
            w_out[wb + t2] = w2[q];
            unsigned short* wbq = w_bf + (((size_t)(b * 4 + q)) * 1024 + m) * 128;
            wbq[t1] = f2bf(w1[q]);
            wbq[t2] = f2bf(w2[q]);
        }
        float red[8];
        #pragma unroll
        for (int r8 = 0; r8 < 8; ++r8) {
            int q = r8 >> 1, p = r8 & 1;
            float v = w1[q] * c1v[p] + w2[q] * c2v[p];
            #pragma unroll
            for (int off = 32; off > 0; off >>= 1) v += __shfl_xor(v, off, 64);
            red[r8] = v;
        }
        if (lane == 0) {
            #pragma unroll
            for (int r8 = 0; r8 < 8; ++r8) wc8[((size_t)b * MM + m) * 8 + r8] = red[r8];
        }
        return;
    }

    // ---- k_A2m branch (staged A+B, LDS-repacked epilogue) ----
    unsigned short* Ah = SM;
    unsigned short* Al = SM + 4096;
    unsigned short* Bh = SM + 8192;
    unsigned short* Bl = SM + 12288;
    int blk = gblk;                  // b*16 + nt
    int b = blk >> 4, nt = blk & 15;
    int n0 = nt * 128;
    int lane = tid & 63, wv = tid >> 6;
    int wm = wv & 1, wn = wv >> 1;

    floatx4 acc[16];
    #pragma unroll
    for (int i = 0; i < 16; ++i) acc[i] = (floatx4){0.f, 0.f, 0.f, 0.f};

    int srow = tid >> 1, shalf = tid & 1;
    const unsigned short* gxh = xh + ((size_t)(b * TT + srow) * 256 + shalf * 16);
    const unsigned short* gxl = xl + ((size_t)(b * TT + srow) * 256 + shalf * 16);
    const unsigned short* gph = pwh + ((size_t)(n0 + srow) * 256 + shalf * 16);
    const unsigned short* gpl = pwl + ((size_t)(n0 + srow) * 256 + shalf * 16);
    int wAd0 = swzk(srow, 2 * shalf);
    int wAd1 = swzk(srow, 2 * shalf + 1);

    int ra = wm * 64 + (lane & 15);
    int rb = wn * 64 + (lane & 15);
    int cq = lane >> 4;

    for (int kc = 0; kc < 256; kc += 32) {
        uint4 a0 = *(const uint4*)(gxh + kc);
        uint4 a1 = *(const uint4*)(gxh + kc + 8);
        uint4 a2 = *(const uint4*)(gxl + kc);
        uint4 a3 = *(const uint4*)(gxl + kc + 8);
        uint4 b0 = *(const uint4*)(gph + kc);
        uint4 b1 = *(const uint4*)(gph + kc + 8);
        uint4 b2 = *(const uint4*)(gpl + kc);
        uint4 b3 = *(const uint4*)(gpl + kc + 8);
        *(uint4*)&Ah[wAd0] = a0; *(uint4*)&Ah[wAd1] = a1;
        *(uint4*)&Al[wAd0] = a2; *(uint4*)&Al[wAd1] = a3;
        *(uint4*)&Bh[wAd0] = b0; *(uint4*)&Bh[wAd1] = b1;
        *(uint4*)&Bl[wAd0] = b2; *(uint4*)&Bl[wAd1] = b3;
        __syncthreads();
        short8 afh[4], afl[4], bfh[4], bfl[4];
        #pragma unroll
        for (int i = 0; i < 4; ++i) {
            afh[i] = *(const short8*)&Ah[swzk(ra + i * 16, cq)];
            afl[i] = *(const short8*)&Al[swzk(ra + i * 16, cq)];
            bfh[i] = *(const short8*)&Bh[swzk(rb + i * 16, cq)];
            bfl[i] = *(const short8*)&Bl[swzk(rb + i * 16, cq)];
        }
        #pragma unroll
        for (int i = 0; i < 4; ++i)
            #pragma unroll
            for (int j = 0; j < 4; ++j) {
                floatx4 c = acc[i * 4 + j];
                c = __builtin_amdgcn_mfma_f32_16x16x32_bf16(afh[i], bfh[j], c, 0, 0, 0);
                c = __builtin_amdgcn_mfma_f32_16x16x32_bf16(afh[i], bfl[j], c, 0, 0, 0);
                c = __builtin_amdgcn_mfma_f32_16x16x32_bf16(afl[i], bfh[j], c, 0, 0, 0);
                acc[i * 4 + j] = c;
            }
        __syncthreads();
    }

    unsigned short* OT = SM;   // [128 n][128 t]
    #pragma unroll
    for (int i = 0; i < 4; ++i)
        #pragma unroll
        for (int j = 0; j < 4; ++j) {
            int nloc = wn * 64 + j * 16 + (lane & 15);
            int tb = wm * 64 + i * 16 + ((lane >> 4) << 2);
            union { unsigned short us[4]; uint2 v; } pk;
            #pragma unroll
            for (int r = 0; r < 4; ++r) pk.us[r] = f2bf(acc[i * 4 + j][r]);
            int chunk = tb >> 3, sub = tb & 7;
            *(uint2*)&OT[nloc * 128 + (((chunk ^ (nloc & 15)) << 3) | sub)] = pk.v;
        }
    __syncthreads();
    int q = n0 >> 9, jb = n0 & 511;
    for (int u = tid; u < 2048; u += 256) {
        int nrow = u >> 4, seg = u & 15;
        uint4 v = *(const uint4*)&OT[nrow * 128 + ((seg ^ (nrow & 15)) << 3)];
        *(uint4*)(A2T + (((size_t)(b * 4 + q) * 512) + jb + nrow) * 128 + seg * 8) = v;
    }
}

// o = W @ A2 (MFMA bf16) + wc8@P2o + bvec; masked rows -> pob
// v5 (R15 = R14 resubmit): tile 128x256 — 32 MFMA per barrier-pair (was 16),
// operand loads 268->201 MB. Same R5-proven schedule: in-flight loads (6 uint4)
// never cross a barrier. LDS 60 KB -> 2 blocks/CU; (256,2) grants full VGPR budget.
__global__ __launch_bounds__(256, 2) void k_main(
    const unsigned short* __restrict__ w_bf, const unsigned short* __restrict__ A2T,
    const float* __restrict__ wc8, const float* __restrict__ P2o,
    const float* __restrict__ bvec, const float* __restrict__ pob,
    const int* __restrict__ ml_i, float* __restrict__ o_out) {
    __shared__ __align__(16) unsigned short Asm[2][128 * 40];   // 2 x 10 KB
    __shared__ __align__(16) unsigned short Bsm[2][256 * 40];   // 2 x 20 KB
    int wgid = blockIdx.x;
    int blk = (wgid & 7) * 64 + (wgid >> 3);   // XCD-aware remap (512 % 8 == 0)
    int nt = blk & 1, mt = (blk >> 1) & 7, b = blk >> 4;
    int m0 = mt * 128, n0 = nt * 256;
    int tid = threadIdx.x;
    int ml = ml_i[b];

    if (m0 >= ml) {
        float* pb_s = (float*)&Asm[0][0];        // 256 floats
        pb_s[tid] = pob[n0 + tid];
        __syncthreads();
        int col4 = (tid & 63) * 4;
        float4 pv = *(const float4*)&pb_s[col4];
        for (int r = tid >> 6; r < 128; r += 4) {
            int m = m0 + r;
            if (m < MM)
                *(float4*)(o_out + ((size_t)b * MM + m) * 512 + n0 + col4) = pv;
        }
        return;
    }

    int lane = tid & 63, wv = tid >> 6;
    int wm = wv & 1, wn = wv >> 1;

    floatx4 acc[32];
    #pragma unroll
    for (int i = 0; i < 32; ++i) acc[i] = (floatx4){0.f, 0.f, 0.f, 0.f};

    int rl = lane >> 4;
    int cl = lane & 15;
    int ra = wm * 64 + cl;
    int rb = wn * 128 + cl;

    int srow = tid >> 2, schunk = tid & 3;
    int doff = srow * 40 + schunk * 8;
    const size_t bq4 = (size_t)b * 4;

    // prologue: stage step 0 (q=0, koff=0): A rows srow,+64; B rows srow,+64,+128,+192
    #pragma unroll
    for (int j = 0; j < 2; ++j) {
        int row = srow + j * 64;
        uint4 va = *(const uint4*)(w_bf + ((bq4 + 0) * 1024 + m0 + row) * 128 + schunk * 8);
        *(uint4*)&Asm[0][doff + j * 2560] = va;
    }
    #pragma unroll
    for (int j = 0; j < 4; ++j) {
        int row = srow + j * 64;
        uint4 vb = *(const uint4*)(A2T + ((bq4 + 0) * 512 + n0 + row) * 128 + schunk * 8);
        *(uint4*)&Bsm[0][doff + j * 2560] = vb;
    }
    __syncthreads();

    int cur = 0;
    for (int s = 0; s < 16; ++s) {
        uint4 la[2], lb[4];
        if (s < 15) {
            int q = (s + 1) >> 2, koff = ((s + 1) & 3) * 32;
            #pragma unroll
            for (int j = 0; j < 2; ++j) {
                int row = srow + j * 64;
                la[j] = *(const uint4*)(w_bf +
                    ((bq4 + q) * 1024 + m0 + row) * 128 + koff + schunk * 8);
            }
            #pragma unroll
            for (int j = 0; j < 4; ++j) {
                int row = srow + j * 64;
                lb[j] = *(const uint4*)(A2T +
                    ((bq4 + q) * 512 + n0 + row) * 128 + koff + schunk * 8);
            }
        }
        {
            int co = rl * 8;
            short8 af[4], bfr[8];
            #pragma unroll
            for (int i = 0; i < 4; ++i)
                af[i] = *(const short8*)&Asm[cur][(ra + i * 16) * 40 + co];
            #pragma unroll
            for (int j2 = 0; j2 < 8; ++j2)
                bfr[j2] = *(const short8*)&Bsm[cur][(rb + j2 * 16) * 40 + co];
            #pragma unroll
            for (int i = 0; i < 4; ++i)
                #pragma unroll
                for (int j2 = 0; j2 < 8; ++j2)
                    acc[i * 8 + j2] = __builtin_amdgcn_mfma_f32_16x16x32_bf16(
                        af[i], bfr[j2], acc[i * 8 + j2], 0, 0, 0);
        }
        if (s < 15) {
            #pragma unroll
            for (int j = 0; j < 2; ++j)
                *(uint4*)&Asm[cur ^ 1][doff + j * 2560] = la[j];
            #pragma unroll
            for (int j = 0; j < 4; ++j)
                *(uint4*)&Bsm[cur ^ 1][doff + j * 2560] = lb[j];
        }
        __syncthreads();
        cur ^= 1;
    }

    // epilogue: stage wc8/P2o/bvec/pob slices in LDS (reuse Asm[0]/Bsm[0])
    float* wc8s = (float*)&Asm[0][0];        // [128][8] = 4 KB
    float* P2os = (float*)&Bsm[0][0];        // [8][256] = 8 KB
    float* bvs  = (float*)&Bsm[0][0] + 2048; // [256]
    float* pobs = (float*)&Bsm[0][0] + 2304; // [256] (ends at 10.2 KB < 20 KB)
    for (int e = tid; e < 1024; e += 256) {
        int mm_ = e >> 3, r = e & 7;
        int m = m0 + mm_;
        wc8s[e] = (m < MM) ? wc8[((size_t)b * MM + m) * 8 + r] : 0.f;
    }
    for (int e = tid; e < 2048; e += 256) {
        int r = e >> 8, jj = e & 255;
        P2os[e] = P2o[r * 512 + n0 + jj];
    }
    bvs[tid] = bvec[n0 + tid];
    pobs[tid] = pob[n0 + tid];
    __syncthreads();
    #pragma unroll
    for (int i = 0; i < 4; ++i) {
        #pragma unroll
        for (int j = 0; j < 8; ++j) {
            int nloc = wn * 128 + j * 16 + (lane & 15);
            #pragma unroll
            for (int reg = 0; reg < 4; ++reg) {
                int mloc = wm * 64 + i * 16 + (lane >> 4) * 4 + reg;
                int m = m0 + mloc;
                if (m >= MM) continue;
                float v;
                if (m < ml) {
                    v = acc[i * 8 + j][reg] + bvs[nloc];
                    #pragma unroll
                    for (int r8 = 0; r8 < 8; ++r8)
                        v += wc8s[mloc * 8 + r8] * P2os[r8 * 256 + nloc];
                } else {
                    v = pobs[nloc];
                }
                o_out[((size_t)b * MM + m) * 512 + n0 + nloc] = v;
            }
        }
    }
}

extern "C" void kernel_launch(void* const* d_in, const int* in_sizes, int n_in,
                              void* d_out, int out_size, void* d_ws, size_t ws_size,
                              hipStream_t stream) {
    (void)in_sizes; (void)n_in; (void)out_size; (void)ws_size;
    const float* x      = (const float*)d_in[0];
    const float* dur    = (const float*)d_in[2];
    const int*   xlen   = (const int*)d_in[3];
    const float* proj_w = (const float*)d_in[4];
    const float* proj_b = (const float*)d_in[5];
    const float* conv_w = (const float*)d_in[6];
    const float* conv_b = (const float*)d_in[7];
    const float* conv_g = (const float*)d_in[8];
    const float* conv_be= (const float*)d_in[9];
    const float* q_w1   = (const float*)d_in[10];
    const float* q_b1   = (const float*)d_in[11];
    const float* q_g    = (const float*)d_in[12];
    const float* q_be   = (const float*)d_in[13];
    const float* q_w2   = (const float*)d_in[14];
    const float* q_b2   = (const float*)d_in[15];
    const float* p_w1   = (const float*)d_in[16];
    const float* p_b1   = (const float*)d_in[17];
    const float* p_g    = (const float*)d_in[18];
    const float* p_be   = (const float*)d_in[19];
    const float* p_w2   = (const float*)d_in[20];
    const float* p_b2   = (const float*)d_in[21];
    const float* p1w    = (const float*)d_in[22];
    const float* p1b    = (const float*)d_in[23];
    const float* p2w    = (const float*)d_in[24];
    const float* p2b    = (const float*)d_in[25];
    const float* pow_   = (const float*)d_in[26];
    const float* pob    = (const float*)d_in[27];

    float* ws    = (float*)d_ws;
    float* e_cum = ws + 0;
    float* baseq = ws + 36864;
    float* basep = ws + 53248;
    float* h     = ws + 61440;
    unsigned short* pw_h = (unsigned short*)(ws + 1110016);
    unsigned short* pw_l = (unsigned short*)(ws + 1372160);
    unsigned short* A2T = (unsigned short*)(ws + 1634304);
    float* wc8   = ws + 5828608;
    float* P2o   = ws + 6084608;
    float* bvec  = ws + 6088704;
    int*   ml_i  = (int*)(ws + 6089216);
    float* PWpart= ws + 6090752;
    unsigned short* w_bf = (unsigned short*)(ws + 8187904);
    unsigned short* x_hi = (unsigned short*)(ws + 16576512);
    unsigned short* x_lo = (unsigned short*)(ws + 17100800);

    float* o_out  = (float*)d_out;                  // (B,M,512)
    float* mm_out = o_out + 16384000;               // (B,M,T)
    float* ml_out = o_out + 20480000;               // (B,)
    float* w_out  = o_out + 20480032;               // (B,Q,M,T)

    kF1<<<dim3(800), dim3(256), 0, stream>>>(x, proj_w, proj_b, h,
                                             p1w, pow_, PWpart,
                                             x_hi, x_lo,
                                             dur, e_cum, ml_i, ml_out, w_bf);
    kF2<<<dim3(385), dim3(256), 0, stream>>>(h, conv_w, xlen,
                                             PWpart, pw_h, pw_l,
                                             p2w, pow_, p1b, p2b, pob, P2o, bvec,
                                             conv_b, conv_g, conv_be,
                                             q_w1, q_b1, p_w1, p_b1,
                                             e_cum, dur, baseq, basep);
    kF3<<<dim3(8512), dim3(256), 0, stream>>>(x_hi, x_lo, pw_h, pw_l, A2T,
                                              baseq, basep,
                                              q_w1, q_g, q_be, q_w2, q_b2,
                                              p_w1, p_g, p_be, p_w2, p_b2,
                                              xlen, ml_i, w_out, mm_out, wc8, w_bf);
    k_main<<<dim3(512), dim3(256), 0, stream>>>(w_bf, A2T, wc8, P2o, bvec,
                                                pob, ml_i, o_out);
}

// Round 16
// 371.412 us; speedup vs baseline: 1.0236x; 1.0236x over previous
//
#include <hip/hip_runtime.h>
#include <math.h>

#define BB 32
#define TT 128
#define HH 256
#define MM 1000

typedef __attribute__((ext_vector_type(8))) short short8;
typedef __attribute__((ext_vector_type(4))) float floatx4;

__device__ inline void fma4(float4& a, const float4 b, float s) {
    a.x += b.x * s; a.y += b.y * s; a.z += b.z * s; a.w += b.w * s;
}

__device__ inline unsigned short f2bf(float f) {
    union { float f; unsigned int u; } c; c.f = f;
    unsigned int u = c.u;
    return (unsigned short)((u + 0x7FFFu + ((u >> 16) & 1u)) >> 16);
}

__device__ inline float bf2f(unsigned short h) {
    union { unsigned int u; float f; } c; c.u = ((unsigned int)h) << 16; return c.f;
}

// ---------------- ws layout (floats) ----------------
// e_cum 0 (4096) | baseq 36864 (16384) | basep 53248 (8192)
// h 61440 (1048576)
// pw_h/pw_l @1110016/1372160 | A2T (ushort) @float 1634304 ([(b*4+q)][n=512][t=128])
// wc8 5828608 | P2o 6084608 | bvec 6088704 | ml_i 6089216
// PWpart 6090752 (2097152) | w_bf (ushort) @float 8187904 ([(b*4+q)][1024][128])
// x_hi @16576512 (524288) | x_lo @17100800 (524288)
// high-water: 17,625,088 floats = 70.5 MB
// R16 = byte-exact restore of R13 (session best, 372.4 us): R14/R15's wide tile
// regressed (60 KB LDS -> 2 blocks/CU vs R13's 40 KB @ (256,3) -> 3 blocks/CU).

// ===== kF1: k_h [0,256) | k_pw_part [256,768) | k_xcvt [768,1792) | k_prep [1792,1824)
__global__ __launch_bounds__(256) void kF1(
    const float* __restrict__ x, const float* __restrict__ pw_h_,
    const float* __restrict__ pb_h, float* __restrict__ h,
    const float* __restrict__ p1w, const float* __restrict__ po,
    float* __restrict__ PWpart,
    unsigned short* __restrict__ xh, unsigned short* __restrict__ xl,
    const float* __restrict__ dur, float* __restrict__ e_cum,
    int* __restrict__ ml_i, float* __restrict__ ml_out,
    unsigned short* __restrict__ w_bf) {
    __shared__ __align__(16) float S1[4096];   // 16 KB union
    int gb = blockIdx.x;
    int tid = threadIdx.x;

    if (gb < 256) {
        // ---- k_h: h = x @ proj_w + proj_b ----
        float (*xs)[HH] = (float(*)[HH])S1;
        int b = gb >> 3, tt = gb & 7;
        int t0 = tt * 16;
        for (int e = tid; e < 16 * HH; e += 256) {
            int r = e >> 8, i = e & 255;
            xs[r][i] = x[(b * TT + t0 + r) * HH + i];
        }
        __syncthreads();
        int jg = tid & 63, rg = tid >> 6;
        int j4 = jg * 4;
        float4 bias = *(const float4*)(pb_h + j4);
        float4 acc[4];
        #pragma unroll
        for (int ri = 0; ri < 4; ++ri) acc[ri] = bias;
        #pragma unroll 4
        for (int i = 0; i < HH; ++i) {
            float4 wv = *(const float4*)(pw_h_ + i * HH + j4);
            #pragma unroll
            for (int ri = 0; ri < 4; ++ri) fma4(acc[ri], wv, xs[rg * 4 + ri][i]);
        }
        #pragma unroll
        for (int ri = 0; ri < 4; ++ri)
            *(float4*)(h + (b * TT + t0 + rg * 4 + ri) * HH + j4) = acc[ri];
    } else if (gb < 768) {
        // ---- k_pw_part ----
        float (*S)[64] = (float(*)[64])S1;
        int blk = gb - 256;
        int ks = blk & 3, colT = (blk >> 2) & 7, ht = blk >> 5;
        int q = colT >> 1, j0 = (colT & 1) * 256;
        int h0 = ht * 16, k0 = ks * 64;
        for (int e = tid; e < 1024; e += 256) {
            int r = e >> 6, c = e & 63;
            S[r][c] = p1w[(q * 256 + h0 + r) * 256 + k0 + c];
        }
        __syncthreads();
        int jg = tid & 63, rg = tid >> 6;
        int jcol = j0 + jg * 4;
        float4 acc[4];
        #pragma unroll
        for (int r = 0; r < 4; ++r) acc[r] = make_float4(0, 0, 0, 0);
        float4 nb = *(const float4*)(po + (size_t)k0 * 512 + jcol);
        for (int c = 0; c < 64; ++c) {
            float4 cur = nb;
            if (c < 63) nb = *(const float4*)(po + (size_t)(k0 + c + 1) * 512 + jcol);
            #pragma unroll
            for (int r = 0; r < 4; ++r) fma4(acc[r], cur, S[rg * 4 + r][c]);
        }
        #pragma unroll
        for (int r = 0; r < 4; ++r) {
            int hh = h0 + rg * 4 + r;
            *(float4*)(PWpart + (size_t)ks * 524288 + hh * 2048 + q * 512 + jcol) = acc[r];
        }
    } else if (gb < 1792) {
        // ---- k_xcvt: x -> bf16 hi/lo ----
        int idx = ((gb - 768) * 256 + tid) * 4;
        float4 v = *(const float4*)(x + idx);
        float vv[4] = {v.x, v.y, v.z, v.w};
        union { unsigned short us[4]; uint2 u; } hi, lo;
        #pragma unroll
        for (int k = 0; k < 4; ++k) {
            unsigned short hv = f2bf(vv[k]);
            hi.us[k] = hv;
            lo.us[k] = f2bf(vv[k] - bf2f(hv));
        }
        *(uint2*)(xh + idx) = hi.u;
        *(uint2*)(xl + idx) = lo.u;
    } else {
        // ---- k_prep ----
        int b = gb - 1792;
        if (tid < 64) {
            #pragma unroll
            for (int q = 0; q < 4; ++q) {
                uint4* dst = (uint4*)(w_bf + (((size_t)(b * 4 + q)) * 1024 + 1000) * 128);
                for (int e = tid; e < 384; e += 64) dst[e] = make_uint4(0, 0, 0, 0);
            }
            if (tid == 0) {
                float run = 0.f;
                const float* d = dur + b * TT;
                float* e = e_cum + b * TT;
                for (int t = 0; t < TT; ++t) { run += d[t]; e[t] = run; }
                int ml = (int)rintf(run);
                if (ml > MM) ml = MM;
                if (ml < 0) ml = 0;
                ml_i[b] = ml;
                ml_out[b] = (float)ml;
            }
        }
    }
}

// ===== kF2: k_conv+k_bases fused [0,256) | k_pwt [256,384) | k_small [384] =====
__global__ __launch_bounds__(256) void kF2(
    const float* __restrict__ h, const float* __restrict__ cw,
    const int* __restrict__ xlen,
    const float* __restrict__ PWpart,
    unsigned short* __restrict__ pwh, unsigned short* __restrict__ pwl,
    const float* __restrict__ p2w, const float* __restrict__ po,
    const float* __restrict__ p1b, const float* __restrict__ p2b,
    const float* __restrict__ pob,
    float* __restrict__ P2o, float* __restrict__ bvec,
    const float* __restrict__ cb, const float* __restrict__ cg,
    const float* __restrict__ cbeta,
    const float* __restrict__ qw1, const float* __restrict__ qb1,
    const float* __restrict__ pw1, const float* __restrict__ pb1,
    const float* __restrict__ e_cum, const float* __restrict__ dur,
    float* __restrict__ baseq, float* __restrict__ basep) {
    __shared__ __align__(16) float S2[10906];   // 43.6 KB union
    int gb = blockIdx.x;
    int tid = threadIdx.x;

    if (gb < 256) {
        // ---- conv + bases ----
        float (*hs)[257] = (float(*)[257])S2;            // 18*257 = 4626
        float (*cws)[769] = (float(*)[769])(S2 + 4626);  // 8*769  = 6152
        float (*hc)[8] = (float(*)[8])(S2 + 10778);      // 16*8   = 128
        int b = gb >> 3, tt = gb & 7;
        int t0 = tt * 16;
        int L = xlen[b];
        for (int e = tid; e < 18 * 256; e += 256) {
            int r = e >> 8, i = e & 255;
            int t = t0 - 1 + r;
            float v = 0.f;
            if (t >= 0 && t < TT && t < L) v = h[((size_t)b * TT + t) * HH + i];
            hs[r][i] = v;
        }
        for (int e = tid; e < 6144; e += 256) {
            int o = e / 768, rem = e - o * 768;
            cws[o][rem] = cw[e];
        }
        __syncthreads();
        if (tid < 128) {
            int o = tid >> 4, tl = tid & 15;
            float acc = 0.f;
            #pragma unroll
            for (int k = 0; k < 3; ++k) {
                const float* wr = &cws[o][k];
                const float* hr = hs[tl + k];
                #pragma unroll 8
                for (int i = 0; i < 256; ++i) acc += hr[i] * wr[i * 3];
            }
            hc[tl][o] = acc;
        }
        __syncthreads();
        if (tid < 16) {
            int t = t0 + tid;
            float v[8];
            float mu = 0.f;
            #pragma unroll
            for (int o = 0; o < 8; ++o) { v[o] = hc[tid][o] + cb[o]; mu += v[o]; }
            mu *= 0.125f;
            float var = 0.f;
            #pragma unroll
            for (int o = 0; o < 8; ++o) { float d = v[o] - mu; var += d * d; }
            var *= 0.125f;
            float rs = 1.0f / sqrtf(var + 1e-5f);
            float valid = (t < L) ? 1.f : 0.f;
            #pragma unroll
            for (int o = 0; o < 8; ++o) {
                float a = (v[o] - mu) * rs * cg[o] + cbeta[o];
                v[o] = a / (1.f + expf(-a)) * valid;
            }
            float e = e_cum[b * TT + t];
            float s_ = e - dur[b * TT + t];
            #pragma unroll
            for (int j = 0; j < 4; ++j) {
                float acc = qb1[j];
                #pragma unroll
                for (int o = 0; o < 8; ++o) acc += v[o] * qw1[o * 4 + j];
                acc += e * qw1[9 * 4 + j] - s_ * qw1[8 * 4 + j];
                baseq[(b * TT + t) * 4 + j] = acc;
            }
            #pragma unroll
            for (int j = 0; j < 2; ++j) {
                float acc = pb1[j];
                #pragma unroll
                for (int o = 0; o < 8; ++o) acc += v[o] * pw1[o * 2 + j];
                acc += e * pw1[9 * 2 + j] - s_ * pw1[8 * 2 + j];
                basep[(b * TT + t) * 2 + j] = acc;
            }
        }
    } else if (gb < 384) {
        // ---- k_pwt ----
        float (*S)[65] = (float(*)[65])S2;   // 64*65 = 4160
        int blk = gb - 256;
        int nt = blk & 31, ct = blk >> 5;
        int c0 = ct * 64, n0 = nt * 64;
        for (int e = tid; e < 4096; e += 256) {
            int cc = e >> 6, nn = e & 63;
            size_t off = (size_t)(c0 + cc) * 2048 + n0 + nn;
            float v = PWpart[off] + PWpart[524288 + off]
                    + PWpart[2 * 524288 + off] + PWpart[3 * 524288 + off];
            S[cc][nn] = v;
        }
        __syncthreads();
        for (int e = tid; e < 4096; e += 256) {
            int nn = e >> 6, cc = e & 63;
            float v = S[cc][nn];
            unsigned short hv = f2bf(v);
            size_t d = (size_t)(n0 + nn) * 256 + c0 + cc;
            pwh[d] = hv;
            pwl[d] = f2bf(v - bf2f(hv));
        }
    } else {
        // ---- k_small, 256-thread variant ----
        for (int j = tid; j < 512; j += 256) {
            float acc[9];
            #pragma unroll
            for (int r = 0; r < 9; ++r) acc[r] = 0.f;
            for (int c = 0; c < HH; ++c) {
                float pv = po[c * 512 + j];
                #pragma unroll
                for (int r = 0; r < 8; ++r) acc[r] += p2w[r * HH + c] * pv;
                acc[8] += (p1b[c] + p2b[c]) * pv;
            }
            #pragma unroll
            for (int r = 0; r < 8; ++r) P2o[r * 512 + j] = acc[r];
            bvec[j] = acc[8] + pob[j];
        }
    }
}

// XOR-swizzled ushort index into a [128 rows][32 k] LDS tile (16B chunk granularity).
__device__ inline int swzk(int row, int chunk) {
    return row * 32 + ((chunk ^ ((row >> 1) & 3)) << 3);
}

// ===== kF3: k_A2m [0,512) | k_wsoft [512,8512) =====  (R11/R13-proven form)
__global__ __launch_bounds__(256) void kF3(
    const unsigned short* __restrict__ xh, const unsigned short* __restrict__ xl,
    const unsigned short* __restrict__ pwh, const unsigned short* __restrict__ pwl,
    unsigned short* __restrict__ A2T,
    const float* __restrict__ baseq, const float* __restrict__ basep,
    const float* __restrict__ qw1, const float* __restrict__ qg,
    const float* __restrict__ qbeta, const float* __restrict__ qw2,
    const float* __restrict__ qb2,
    const float* __restrict__ pw1, const float* __restrict__ pg,
    const float* __restrict__ pbeta, const float* __restrict__ pw2,
    const float* __restrict__ pb2,
    const int* __restrict__ xlen, const int* __restrict__ ml_i,
    float* __restrict__ w_out, float* __restrict__ mm_out,
    float* __restrict__ wc8, unsigned short* __restrict__ w_bf) {
    __shared__ __align__(16) unsigned short SM[16384];   // 32 KB (A2m branch only)
    int gblk = blockIdx.x;
    int tid = threadIdx.x;

    if (gblk >= 512) {
        // ---- wsoft branch (barrier-free, R9-proven body) ----
        int blk = gblk - 512;            // b*250 + mg
        int b = blk / 250;
        int mg = blk - b * 250;
        int wv = tid >> 6, lane = tid & 63;
        int m = mg * 4 + wv;
        int ml = ml_i[b];
        int t1 = lane, t2 = lane + 64;
        bool pad = (m >= ml);
        size_t mmbase = ((size_t)b * MM + m) * TT;
        mm_out[mmbase + t1] = pad ? 1.f : 0.f;
        mm_out[mmbase + t2] = pad ? 1.f : 0.f;
        if (pad) {
            #pragma unroll
            for (int q = 0; q < 4; ++q) {
                size_t wb = ((size_t)(b * 4 + q) * MM + m) * TT;
                w_out[wb + t1] = 0.f;
                w_out[wb + t2] = 0.f;
                unsigned short* wbq = w_bf + (((size_t)(b * 4 + q)) * 1024 + m) * 128;
                wbq[t1] = 0; wbq[t2] = 0;
            }
            if (lane == 0) {
                #pragma unroll
                for (int r = 0; r < 8; ++r) wc8[((size_t)b * MM + m) * 8 + r] = 0.f;
            }
            return;
        }
        int L = xlen[b];
        float mp1 = (float)(m + 1);
        float dq[4];
        #pragma unroll
        for (int j = 0; j < 4; ++j) dq[j] = mp1 * (qw1[8 * 4 + j] - qw1[9 * 4 + j]);

        float sc1[4], sc2[4];
        float c1v[2], c2v[2];
        #pragma unroll
        for (int half = 0; half < 2; ++half) {
            int t = half ? t2 : t1;
            float* sc = half ? sc2 : sc1;
            float* cv = half ? c2v : c1v;
            if (t < L) {
                float4 bq = *(const float4*)(baseq + ((size_t)b * TT + t) * 4);
                float z[4] = {bq.x + dq[0], bq.y + dq[1], bq.z + dq[2], bq.w + dq[3]};
                float mu = 0.25f * (z[0] + z[1] + z[2] + z[3]);
                float var = 0.f;
                #pragma unroll
                for (int j = 0; j < 4; ++j) { float d = z[j] - mu; var += d * d; }
                var *= 0.25f;
                float rs = 1.f / sqrtf(var + 1e-5f);
                float a[4];
                #pragma unroll
                for (int j = 0; j < 4; ++j) {
                    float av = (z[j] - mu) * rs * qg[j] + qbeta[j];
                    a[j] = av / (1.f + expf(-av));
                }
                #pragma unroll
                for (int q = 0; q < 4; ++q) {
                    float s = qb2[q];
                    #pragma unroll
                    for (int j = 0; j < 4; ++j) s += a[j] * qw2[j * 4 + q];
                    sc[q] = s;
                }
                float z0 = basep[((size_t)b * TT + t) * 2 + 0] + mp1 * (pw1[16] - pw1[18]);
                float z1 = basep[((size_t)b * TT + t) * 2 + 1] + mp1 * (pw1[17] - pw1[19]);
                float pmu = 0.5f * (z0 + z1);
                float d0 = z0 - pmu, d1 = z1 - pmu;
                float pvar = 0.5f * (d0 * d0 + d1 * d1);
                float prs = 1.f / sqrtf(pvar + 1e-5f);
                float a0 = d0 * prs * pg[0] + pbeta[0];
                float a1 = d1 * prs * pg[1] + pbeta[1];
                a0 = a0 / (1.f + expf(-a0));
                a1 = a1 / (1.f + expf(-a1));
                cv[0] = pb2[0] + a0 * pw2[0] + a1 * pw2[2];
                cv[1] = pb2[1] + a0 * pw2[1] + a1 * pw2[3];
            } else {
                sc[0] = sc[1] = sc[2] = sc[3] = -__builtin_inff();
                cv[0] = cv[1] = 0.f;
            }
        }
        float w1[4], w2[4];
        #pragma unroll
        for (int q = 0; q < 4; ++q) {
            float mx = fmaxf(sc1[q], sc2[q]);
            #pragma unroll
            for (int off = 32; off > 0; off >>= 1) mx = fmaxf(mx, __shfl_xor(mx, off, 64));
            float e1 = expf(sc1[q] - mx);
            float e2 = expf(sc2[q] - mx);
            float s = e1 + e2;
            #pragma unroll
            for (int off = 32; off > 0; off >>= 1) s += __shfl_xor(s, off, 64);
            w1[q] = e1 / s;
            w2[q] = e2 / s;
            size_t wb = ((size_t)(b * 4 + q) * MM + m) * TT;
            w_out[wb + t1] = w1[q];
            w_out[wb + t2] = w2[q];
            unsigned short* wbq = w_bf + (((size_t)(b * 4 + q)) * 1024 + m) * 128;
            wbq[t1] = f2bf(w1[q]);
            wbq[t2] = f2bf(w2[q]);
        }
        float red[8];
        #pragma unroll
        for (int r8 = 0; r8 < 8; ++r8) {
            int q = r8 >> 1, p = r8 & 1;
            float v = w1[q] * c1v[p] + w2[q] * c2v[p];
            #pragma unroll
            for (int off = 32; off > 0; off >>= 1) v += __shfl_xor(v, off, 64);
            red[r8] = v;
        }
        if (lane == 0) {
            #pragma unroll
            for (int r8 = 0; r8 < 8; ++r8) wc8[((size_t)b * MM + m) * 8 + r8] = red[r8];
        }
        return;
    }

    // ---- k_A2m branch (staged A+B, LDS-repacked epilogue) ----
    unsigned short* Ah = SM;
    unsigned short* Al = SM + 4096;
    unsigned short* Bh = SM + 8192;
    unsigned short* Bl = SM + 12288;
    int blk = gblk;                  // b*16 + nt
    int b = blk >> 4, nt = blk & 15;
    int n0 = nt * 128;
    int lane = tid & 63, wv = tid >> 6;
    int wm = wv & 1, wn = wv >> 1;

    floatx4 acc[16];
    #pragma unroll
    for (int i = 0; i < 16; ++i) acc[i] = (floatx4){0.f, 0.f, 0.f, 0.f};

    int srow = tid >> 1, shalf = tid & 1;
    const unsigned short* gxh = xh + ((size_t)(b * TT + srow) * 256 + shalf * 16);
    const unsigned short* gxl = xl + ((size_t)(b * TT + srow) * 256 + shalf * 16);
    const unsigned short* gph = pwh + ((size_t)(n0 + srow) * 256 + shalf * 16);
    const unsigned short* gpl = pwl + ((size_t)(n0 + srow) * 256 + shalf * 16);
    int wAd0 = swzk(srow, 2 * shalf);
    int wAd1 = swzk(srow, 2 * shalf + 1);

    int ra = wm * 64 + (lane & 15);
    int rb = wn * 64 + (lane & 15);
    int cq = lane >> 4;

    for (int kc = 0; kc < 256; kc += 32) {
        uint4 a0 = *(const uint4*)(gxh + kc);
        uint4 a1 = *(const uint4*)(gxh + kc + 8);
        uint4 a2 = *(const uint4*)(gxl + kc);
        uint4 a3 = *(const uint4*)(gxl + kc + 8);
        uint4 b0 = *(const uint4*)(gph + kc);
        uint4 b1 = *(const uint4*)(gph + kc + 8);
        uint4 b2 = *(const uint4*)(gpl + kc);
        uint4 b3 = *(const uint4*)(gpl + kc + 8);
        *(uint4*)&Ah[wAd0] = a0; *(uint4*)&Ah[wAd1] = a1;
        *(uint4*)&Al[wAd0] = a2; *(uint4*)&Al[wAd1] = a3;
        *(uint4*)&Bh[wAd0] = b0; *(uint4*)&Bh[wAd1] = b1;
        *(uint4*)&Bl[wAd0] = b2; *(uint4*)&Bl[wAd1] = b3;
        __syncthreads();
        short8 afh[4], afl[4], bfh[4], bfl[4];
        #pragma unroll
        for (int i = 0; i < 4; ++i) {
            afh[i] = *(const short8*)&Ah[swzk(ra + i * 16, cq)];
            afl[i] = *(const short8*)&Al[swzk(ra + i * 16, cq)];
            bfh[i] = *(const short8*)&Bh[swzk(rb + i * 16, cq)];
            bfl[i] = *(const short8*)&Bl[swzk(rb + i * 16, cq)];
        }
        #pragma unroll
        for (int i = 0; i < 4; ++i)
            #pragma unroll
            for (int j = 0; j < 4; ++j) {
                floatx4 c = acc[i * 4 + j];
                c = __builtin_amdgcn_mfma_f32_16x16x32_bf16(afh[i], bfh[j], c, 0, 0, 0);
                c = __builtin_amdgcn_mfma_f32_16x16x32_bf16(afh[i], bfl[j], c, 0, 0, 0);
                c = __builtin_amdgcn_mfma_f32_16x16x32_bf16(afl[i], bfh[j], c, 0, 0, 0);
                acc[i * 4 + j] = c;
            }
        __syncthreads();
    }

    unsigned short* OT = SM;   // [128 n][128 t]
    #pragma unroll
    for (int i = 0; i < 4; ++i)
        #pragma unroll
        for (int j = 0; j < 4; ++j) {
            int nloc = wn * 64 + j * 16 + (lane & 15);
            int tb = wm * 64 + i * 16 + ((lane >> 4) << 2);
            union { unsigned short us[4]; uint2 v; } pk;
            #pragma unroll
            for (int r = 0; r < 4; ++r) pk.us[r] = f2bf(acc[i * 4 + j][r]);
            int chunk = tb >> 3, sub = tb & 7;
            *(uint2*)&OT[nloc * 128 + (((chunk ^ (nloc & 15)) << 3) | sub)] = pk.v;
        }
    __syncthreads();
    int q = n0 >> 9, jb = n0 & 511;
    for (int u = tid; u < 2048; u += 256) {
        int nrow = u >> 4, seg = u & 15;
        uint4 v = *(const uint4*)&OT[nrow * 128 + ((seg ^ (nrow & 15)) << 3)];
        *(uint4*)(A2T + (((size_t)(b * 4 + q) * 512) + jb + nrow) * 128 + seg * 8) = v;
    }
}

// o = W @ A2 (MFMA bf16) + wc8@P2o + bvec; masked rows -> pob
// R13-proven: 128x128 tile, K=32 dbuf, loads never cross a barrier, (256,3).
__global__ __launch_bounds__(256, 3) void k_main(
    const unsigned short* __restrict__ w_bf, const unsigned short* __restrict__ A2T,
    const float* __restrict__ wc8, const float* __restrict__ P2o,
    const float* __restrict__ bvec, const float* __restrict__ pob,
    const int* __restrict__ ml_i, float* __restrict__ o_out) {
    __shared__ __align__(16) unsigned short Asm[2][128 * 40];   // 2 x 10 KB
    __shared__ __align__(16) unsigned short Bsm[2][128 * 40];   // 2 x 10 KB
    int wgid = blockIdx.x;
    int blk = (wgid & 7) * 128 + (wgid >> 3);   // XCD-aware remap
    int nt = blk & 3, mt = (blk >> 2) & 7, b = blk >> 5;
    int m0 = mt * 128, n0 = nt * 128;
    int tid = threadIdx.x;
    int ml = ml_i[b];

    if (m0 >= ml) {
        float* pb_s = (float*)&Asm[0][0];
        if (tid < 128) pb_s[tid] = pob[n0 + tid];
        __syncthreads();
        int col4 = (tid & 31) * 4;
        float4 pv = *(const float4*)&pb_s[col4];
        for (int r = tid >> 5; r < 128; r += 8) {
            int m = m0 + r;
            if (m < MM)
                *(float4*)(o_out + ((size_t)b * MM + m) * 512 + n0 + col4) = pv;
        }
        return;
    }

    int lane = tid & 63, wv = tid >> 6;
    int wm = wv & 1, wn = wv >> 1;

    floatx4 acc[16];
    #pragma unroll
    for (int i = 0; i < 16; ++i) acc[i] = (floatx4){0.f, 0.f, 0.f, 0.f};

    int rl = lane >> 4;
    int cl = lane & 15;
    int ra = wm * 64 + cl;
    int rb = wn * 64 + cl;

    int srow = tid >> 2, schunk = tid & 3;
    int doff = srow * 40 + schunk * 8;
    const size_t bq4 = (size_t)b * 4;

    #pragma unroll
    for (int j = 0; j < 2; ++j) {
        int row = srow + j * 64;
        uint4 va = *(const uint4*)(w_bf + ((bq4 + 0) * 1024 + m0 + row) * 128 + schunk * 8);
        uint4 vb = *(const uint4*)(A2T + ((bq4 + 0) * 512 + n0 + row) * 128 + schunk * 8);
        *(uint4*)&Asm[0][doff + j * 2560] = va;
        *(uint4*)&Bsm[0][doff + j * 2560] = vb;
    }
    __syncthreads();

    int cur = 0;
    for (int s = 0; s < 16; ++s) {
        uint4 la[2], lb[2];
        if (s < 15) {
            int q = (s + 1) >> 2, koff = ((s + 1) & 3) * 32;
            #pragma unroll
            for (int j = 0; j < 2; ++j) {
                int row = srow + j * 64;
                la[j] = *(const uint4*)(w_bf +
                    ((bq4 + q) * 1024 + m0 + row) * 128 + koff + schunk * 8);
                lb[j] = *(const uint4*)(A2T +
                    ((bq4 + q) * 512 + n0 + row) * 128 + koff + schunk * 8);
            }
        }
        {
            int co = rl * 8;
            short8 af[4], bfr[4];
            #pragma unroll
            for (int i = 0; i < 4; ++i)
                af[i] = *(const short8*)&Asm[cur][(ra + i * 16) * 40 + co];
            #pragma unroll
            for (int j2 = 0; j2 < 4; ++j2)
                bfr[j2] = *(const short8*)&Bsm[cur][(rb + j2 * 16) * 40 + co];
            #pragma unroll
            for (int i = 0; i < 4; ++i)
                #pragma unroll
                for (int j2 = 0; j2 < 4; ++j2)
                    acc[i * 4 + j2] = __builtin_amdgcn_mfma_f32_16x16x32_bf16(
                        af[i], bfr[j2], acc[i * 4 + j2], 0, 0, 0);
        }
        if (s < 15) {
            #pragma unroll
            for (int j = 0; j < 2; ++j) {
                *(uint4*)&Asm[cur ^ 1][doff + j * 2560] = la[j];
                *(uint4*)&Bsm[cur ^ 1][doff + j * 2560] = lb[j];
            }
        }
        __syncthreads();
        cur ^= 1;
    }

    float* wc8s = (float*)&Asm[0][0];
    float* P2os = (float*)&Bsm[0][0];
    float* bvs  = (float*)&Bsm[0][0] + 1024;
    float* pobs = (float*)&Bsm[0][0] + 1152;
    for (int e = tid; e < 1024; e += 256) {
        int mm_ = e >> 3, r = e & 7;
        int m = m0 + mm_;
        wc8s[e] = (m < MM) ? wc8[((size_t)b * MM + m) * 8 + r] : 0.f;
    }
    for (int e = tid; e < 1024; e += 256) {
        int r = e >> 7, j = e & 127;
        P2os[e] = P2o[r * 512 + n0 + j];
    }
    if (tid < 128) {
        bvs[tid] = bvec[n0 + tid];
        pobs[tid] = pob[n0 + tid];
    }
    __syncthreads();
    #pragma unroll
    for (int i = 0; i < 4; ++i) {
        #pragma unroll
        for (int j = 0; j < 4; ++j) {
            int nloc = wn * 64 + j * 16 + (lane & 15);
            #pragma unroll
            for (int reg = 0; reg < 4; ++reg) {
                int mloc = wm * 64 + i * 16 + (lane >> 4) * 4 + reg;
                int m = m0 + mloc;
                if (m >= MM) continue;
                float v;
                if (m < ml) {
                    v = acc[i * 4 + j][reg] + bvs[nloc];
                    #pragma unroll
                    for (int r8 = 0; r8 < 8; ++r8)
                        v += wc8s[mloc * 8 + r8] * P2os[r8 * 128 + nloc];
                } else {
                    v = pobs[nloc];
                }
                o_out[((size_t)b * MM + m) * 512 + n0 + nloc] = v;
            }
        }
    }
}

extern "C" void kernel_launch(void* const* d_in, const int* in_sizes, int n_in,
                              void* d_out, int out_size, void* d_ws, size_t ws_size,
                              hipStream_t stream) {
    (void)in_sizes; (void)n_in; (void)out_size; (void)ws_size;
    const float* x      = (const float*)d_in[0];
    const float* dur    = (const float*)d_in[2];
    const int*   xlen   = (const int*)d_in[3];
    const float* proj_w = (const float*)d_in[4];
    const float* proj_b = (const float*)d_in[5];
    const float* conv_w = (const float*)d_in[6];
    const float* conv_b = (const float*)d_in[7];
    const float* conv_g = (const float*)d_in[8];
    const float* conv_be= (const float*)d_in[9];
    const float* q_w1   = (const float*)d_in[10];
    const float* q_b1   = (const float*)d_in[11];
    const float* q_g    = (const float*)d_in[12];
    const float* q_be   = (const float*)d_in[13];
    const float* q_w2   = (const float*)d_in[14];
    const float* q_b2   = (const float*)d_in[15];
    const float* p_w1   = (const float*)d_in[16];
    const float* p_b1   = (const float*)d_in[17];
    const float* p_g    = (const float*)d_in[18];
    const float* p_be   = (const float*)d_in[19];
    const float* p_w2   = (const float*)d_in[20];
    const float* p_b2   = (const float*)d_in[21];
    const float* p1w    = (const float*)d_in[22];
    const float* p1b    = (const float*)d_in[23];
    const float* p2w    = (const float*)d_in[24];
    const float* p2b    = (const float*)d_in[25];
    const float* pow_   = (const float*)d_in[26];
    const float* pob    = (const float*)d_in[27];

    float* ws    = (float*)d_ws;
    float* e_cum = ws + 0;
    float* baseq = ws + 36864;
    float* basep = ws + 53248;
    float* h     = ws + 61440;
    unsigned short* pw_h = (unsigned short*)(ws + 1110016);
    unsigned short* pw_l = (unsigned short*)(ws + 1372160);
    unsigned short* A2T = (unsigned short*)(ws + 1634304);
    float* wc8   = ws + 5828608;
    float* P2o   = ws + 6084608;
    float* bvec  = ws + 6088704;
    int*   ml_i  = (int*)(ws + 6089216);
    float* PWpart= ws + 6090752;
    unsigned short* w_bf = (unsigned short*)(ws + 8187904);
    unsigned short* x_hi = (unsigned short*)(ws + 16576512);
    unsigned short* x_lo = (unsigned short*)(ws + 17100800);

    float* o_out  = (float*)d_out;                  // (B,M,512)
    float* mm_out = o_out + 16384000;               // (B,M,T)
    float* ml_out = o_out + 20480000;               // (B,)
    float* w_out  = o_out + 20480032;               // (B,Q,M,T)

    kF1<<<dim3(1824), dim3(256), 0, stream>>>(x, proj_w, proj_b, h,
                                              p1w, pow_, PWpart,
                                              x_hi, x_lo,
                                              dur, e_cum, ml_i, ml_out, w_bf);
    kF2<<<dim3(385), dim3(256), 0, stream>>>(h, conv_w, xlen,
                                             PWpart, pw_h, pw_l,
                                             p2w, pow_, p1b, p2b, pob, P2o, bvec,
                                             conv_b, conv_g, conv_be,
                                             q_w1, q_b1, p_w1, p_b1,
                                             e_cum, dur, baseq, basep);
    kF3<<<dim3(8512), dim3(256), 0, stream>>>(x_hi, x_lo, pw_h, pw_l, A2T,
                                              baseq, basep,
                                              q_w1, q_g, q_be, q_w2, q_b2,
                                              p_w1, p_g, p_be, p_w2, p_b2,
                                              xlen, ml_i, w_out, mm_out, wc8, w_bf);
    k_main<<<dim3(BB * 32), dim3(256), 0, stream>>>(w_bf, A2T, wc8, P2o, bvec,
                                                    pob, ml_i, o_out);
}